// Round 20
// baseline (178.288 us; speedup 1.0000x reference)
//
#include <hip/hip_runtime.h>
#include <hip/hip_bf16.h>

#define B_  2
#define S_  2048
#define D_  1024
#define H_  16
#define DK_ 64
#define NR  (B_*S_)   // 4096 rows
#define QT_ 16        // q-tiles of 128 rows per (b,h)
#define CPP 20        // KV-chunk units per (b,h) (pairs of q-tiles)

typedef __bf16 bf16_t;
typedef __attribute__((ext_vector_type(8)))  __bf16 bf16x8;
typedef __attribute__((ext_vector_type(4)))  float  f32x4;
typedef __attribute__((ext_vector_type(16))) float  f32x16;

// Q pre-scale: 1/sqrt(64) * log2(e)  (attention exp computed in exp2 domain)
#define QSCALE (0.125f * 1.44269504088896340736f)

// ---------------------------------------------------------------------------
__device__ inline void gl_lds16(const void* g, void* l) {
  __builtin_amdgcn_global_load_lds(
      (const __attribute__((address_space(1))) void*)g,
      (__attribute__((address_space(3))) void*)l, 16, 0, 0);
}

__device__ inline unsigned pack2(float a, float b) {
  union { bf16_t h[2]; unsigned u; } x;
  x.h[0] = (bf16_t)a; x.h[1] = (bf16_t)b;
  return x.u;
}

// raw hardware exp2 (r12: −12-15us of VALU vs OCML exp2f without -ffast-math)
__device__ inline float fast_exp2(float x) {
  float r;
  asm("v_exp_f32 %0, %1" : "=v"(r) : "v"(x));
  return r;
}

// swizzled LDS fragment reads; XOR involution matches the staging side.
__device__ inline bf16x8 frag(const bf16_t* p, int r, int j) {
  return *(const bf16x8*)(p + r * 64 + ((j ^ (r & 7)) * 8));
}
__device__ inline bf16x8 frag32(const bf16_t* p, int r, int j) {
  return *(const bf16x8*)(p + r * 32 + ((j ^ ((r >> 1) & 3)) * 8));
}

// pair-chunk decode tables (heaviest-first dispatch order)
__device__ const unsigned char ord_p[CPP] = {7,6,5,4,3,2,7,6,5,4,7,6,1,7,5,3,6,4,2,0};
__device__ const unsigned char ord_c[CPP] = {0,0,0,0,0,0,1,1,1,1,2,2,0,3,2,1,3,2,1,0};
__device__ const unsigned char cbase[8]   = {0,1,2,4,6,9,12,16};

// ---------------------------------------------------------------------------
__global__ void transpose_cvt(const float* __restrict__ wq, const float* __restrict__ wk,
                              const float* __restrict__ wv,
                              bf16_t* __restrict__ oq, bf16_t* __restrict__ ok,
                              bf16_t* __restrict__ ov) {
  const int z = blockIdx.z;
  const float* W = z == 0 ? wq : z == 1 ? wk : wv;
  bf16_t*     WT = z == 0 ? oq : z == 1 ? ok : ov;
  __shared__ float t[32][33];
  int x  = blockIdx.x * 32 + threadIdx.x;
  int y0 = blockIdx.y * 32;
  for (int i = threadIdx.y; i < 32; i += 8)
    t[i][threadIdx.x] = W[(size_t)(y0 + i) * D_ + x];
  __syncthreads();
  int k  = y0 + threadIdx.x;
  int n0 = blockIdx.x * 32;
  for (int i = threadIdx.y; i < 32; i += 8)
    WT[(size_t)(n0 + i) * D_ + k] = (bf16_t)t[threadIdx.x][i];
}

// ---------------------------------------------------------------------------
// C = relu(X @ W + bias) [* scale]; fused fp32-X read (r16 structure, best
// measured total). A: reg-staged fp32->bf16, swizzled LDS write, 1-deep.
// B: global_load_lds, 2-deep, pre-swizzled source. BK=32, 3 buffers.
// ---------------------------------------------------------------------------
struct AReg { float4 a[4]; };

__global__ __launch_bounds__(256, 3) void gemm_qkv(
    const float* __restrict__ XFq, const float* __restrict__ XFk, const float* __restrict__ XFv,
    const bf16_t* __restrict__ Wq, const bf16_t* __restrict__ Wk, const bf16_t* __restrict__ Wv,
    const float* __restrict__ bq, const float* __restrict__ bk, const float* __restrict__ bv,
    bf16_t* __restrict__ Yq, bf16_t* __restrict__ Yk, bf16_t* __restrict__ Yv)
{
  const int z = blockIdx.z;
  const float*  XF   = z == 0 ? XFq : z == 1 ? XFk : XFv;
  const bf16_t* WT   = z == 0 ? Wq : z == 1 ? Wk : Wv;
  const float*  bias = z == 0 ? bq : z == 1 ? bk : bv;
  bf16_t*       Y    = z == 0 ? Yq : z == 1 ? Yk : Yv;
  const float scale  = z == 0 ? QSCALE : 1.0f;
  const int transposedV = (z == 2);

  __shared__ bf16_t As[3][128 * 32];
  __shared__ bf16_t Bs[3][128 * 32];
  const int m0 = blockIdx.x * 128, n0 = blockIdx.y * 128;
  const int t = threadIdx.x, l = t & 63, w = t >> 6;
  const int wm = (w & 1) * 64, wn = (w >> 1) * 64;
  const int lr = l & 15, lg4 = l >> 4;

  f32x4 acc[4][4] = {};

  auto loadA = [&](int k0) {
    AReg r;
    #pragma unroll
    for (int i = 0; i < 2; i++) {
      int c = i * 256 + t;
      int row = c >> 2, j = c & 3;
      const float* src = XF + (size_t)(m0 + row) * D_ + k0 + j * 8;
      r.a[2 * i]     = *(const float4*)src;
      r.a[2 * i + 1] = *(const float4*)(src + 4);
    }
    return r;
  };
  auto cvtWriteA = [&](int bi, const AReg& r) {
    #pragma unroll
    for (int i = 0; i < 2; i++) {
      int c = i * 256 + t;
      int row = c >> 2, j = c & 3;
      union { bf16_t h[8]; bf16x8 v; } pk;
      #pragma unroll
      for (int k = 0; k < 4; k++) {
        pk.h[k]     = (bf16_t)r.a[2 * i][k];
        pk.h[4 + k] = (bf16_t)r.a[2 * i + 1][k];
      }
      *(bf16x8*)&As[bi][row * 32 + ((j ^ ((row >> 1) & 3)) * 8)] = pk.v;
    }
  };
  auto stageB = [&](int bi, int k0) {
    #pragma unroll
    for (int i = 0; i < 2; i++) {
      int c = i * 256 + t;
      int row = c >> 2, j = c & 3;
      int sc = (j ^ ((row >> 1) & 3)) * 8;
      gl_lds16(WT + (size_t)(n0 + row) * D_ + k0 + sc, &Bs[bi][c * 8]);
    }
  };

  AReg aA = loadA(0);
  stageB(0, 0);
  AReg aNext = loadA(32);
  stageB(1, 32);
  cvtWriteA(0, aA);
  asm volatile("s_waitcnt vmcnt(6) lgkmcnt(0)" ::: "memory");
  __builtin_amdgcn_s_barrier();
  __builtin_amdgcn_sched_barrier(0);

  const int NSTEP = D_ / 32;
  for (int p = 0; p < NSTEP; ++p) {
    const int cur = p - (p / 3) * 3;

    AReg aNew;
    const bool more = (p + 2 < NSTEP);
    if (more) {
      const int nb = (p + 2) - ((p + 2) / 3) * 3;
      aNew = loadA((p + 2) * 32);
      stageB(nb, (p + 2) * 32);
    }

    bf16x8 af[4], bfr[4];
    #pragma unroll
    for (int mf = 0; mf < 4; mf++)
      af[mf] = frag32(&As[cur][0], wm + mf * 16 + lr, lg4);
    #pragma unroll
    for (int nf = 0; nf < 4; nf++)
      bfr[nf] = frag32(&Bs[cur][0], wn + nf * 16 + lr, lg4);
    __builtin_amdgcn_s_setprio(1);
    #pragma unroll
    for (int mf = 0; mf < 4; mf++)
      #pragma unroll
      for (int nf = 0; nf < 4; nf++)
        acc[mf][nf] = __builtin_amdgcn_mfma_f32_16x16x32_bf16(
            af[mf], bfr[nf], acc[mf][nf], 0, 0, 0);
    __builtin_amdgcn_s_setprio(0);

    if (p + 1 < NSTEP) {
      const int nb1 = (p + 1) - ((p + 1) / 3) * 3;
      cvtWriteA(nb1, aNext);
      if (more) asm volatile("s_waitcnt vmcnt(6) lgkmcnt(0)" ::: "memory");
      else      asm volatile("s_waitcnt vmcnt(0) lgkmcnt(0)" ::: "memory");
      __builtin_amdgcn_s_barrier();
      __builtin_amdgcn_sched_barrier(0);
      aNext = aNew;
    }
  }

  #pragma unroll
  for (int nf = 0; nf < 4; nf++) {
    int col = n0 + wn + nf * 16 + lr;
    float bvv = bias[col];
    #pragma unroll
    for (int mf = 0; mf < 4; mf++) {
      if (!transposedV) {
        #pragma unroll
        for (int r = 0; r < 4; r++) {
          int row = m0 + wm + mf * 16 + lg4 * 4 + r;
          float v = fmaxf(acc[mf][nf][r] + bvv, 0.f) * scale;
          Y[(size_t)row * D_ + col] = (bf16_t)v;
        }
      } else {
        int row0 = m0 + wm + mf * 16 + lg4 * 4;
        int bb = row0 >> 11, s0 = row0 & (S_ - 1);
        int hh = col >> 6,  dk = col & (DK_ - 1);
        union { bf16_t h[4]; unsigned long long u; } pk;
        #pragma unroll
        for (int r = 0; r < 4; r++)
          pk.h[r] = (bf16_t)fmaxf(acc[mf][nf][r] + bvv, 0.f);
        *(unsigned long long*)&Y[(((size_t)(bb * H_ + hh)) * DK_ + dk) * S_ + s0] = pk.u;
      }
    }
  }
}

// ---------------------------------------------------------------------------
// attention helpers
// ---------------------------------------------------------------------------
__device__ inline void qkt(const bf16_t* kl, const bf16x8* qf, int lq, int hh,
                           f32x16& s0, f32x16& s1) {
  #pragma unroll
  for (int s = 0; s < 4; s++) {
    bf16x8 k0 = frag(kl, lq, 2 * s + hh);
    bf16x8 k1 = frag(kl, lq + 32, 2 * s + hh);
    s0 = __builtin_amdgcn_mfma_f32_32x32x16_bf16(k0, qf[s], s0, 0, 0, 0);
    s1 = __builtin_amdgcn_mfma_f32_32x32x16_bf16(k1, qf[s], s1, 0, 0, 0);
  }
}

__device__ inline void cmask(f32x16& s0, f32x16& s1, int kb, int q, int hh) {
  #pragma unroll
  for (int r = 0; r < 16; r++) {
    int krow = kb + (r & 3) + 8 * (r >> 2) + 4 * hh;
    if (krow > q)      s0[r] = -1e30f;
    if (krow + 32 > q) s1[r] = -1e30f;
  }
}

__device__ inline void pv_quad(const f32x16& p0, const f32x16& p1,
                               const bf16_t* vl, int lq, int hh,
                               f32x16& o0, f32x16& o1) {
  #pragma unroll
  for (int st = 0; st < 4; st++) {
    const f32x16& ps = (st < 2) ? p0 : p1;
    const int bb = (st & 1) * 8;
    unsigned lo0 = pack2(ps[bb + 0], ps[bb + 1]), lo1 = pack2(ps[bb + 2], ps[bb + 3]);
    unsigned hi0 = pack2(ps[bb + 4], ps[bb + 5]), hi1 = pack2(ps[bb + 6], ps[bb + 7]);
    unsigned sA = hh ? lo0 : hi0, sB = hh ? lo1 : hi1;
    unsigned rA = __shfl_xor(sA, 32, 64), rB = __shfl_xor(sB, 32, 64);
    union { unsigned u[4]; bf16x8 v; } pf;
    pf.u[0] = hh ? rA : lo0;  pf.u[1] = hh ? rB : lo1;
    pf.u[2] = hh ? hi0 : rA;  pf.u[3] = hh ? hi1 : rB;
    bf16x8 v0 = frag(vl, lq, 2 * st + hh);
    bf16x8 v1 = frag(vl, lq + 32, 2 * st + hh);
    o0 = __builtin_amdgcn_mfma_f32_32x32x16_bf16(v0, pf.v, o0, 0, 0, 0);
    o1 = __builtin_amdgcn_mfma_f32_32x32x16_bf16(v1, pf.v, o1, 0, 0, 0);
  }
}

// ---------------------------------------------------------------------------
// causal flash attention (r18 structure) + IN-KERNEL LAST-FINISHER COMBINE:
// each (bh,pair) chunk block writes partials, fences, atomicAdd's a counter;
// the block seeing old==nc-1 (still running -> no spin/deadlock) merges all
// chunk partials for both q-tiles of its pair and writes fp32 out.
// Device-scope fence+atomic = cross-XCD safe (G16). Fixed reduction order
// -> bit-deterministic regardless of which block combines.
// ---------------------------------------------------------------------------
__global__ __launch_bounds__(512, 2) void attn_fwd(
    const bf16_t* __restrict__ Q, const bf16_t* __restrict__ K,
    const bf16_t* __restrict__ VT, bf16_t* __restrict__ PO,
    float* __restrict__ PL, int* __restrict__ CNT, float* __restrict__ out)
{
  __shared__ bf16_t lbuf[2][16384];
  __shared__ int lastFlag;

  const int bx = blockIdx.x;
  const int unit = bx >> 5, bh = bx & 31;
  const int p_ = ord_p[unit], ch = ord_c[unit];
  const int b = bh >> 4, h = bh & 15;
  const int kt0 = ch * 8;
  const int nt = min(8, (4 * p_ + 4) - kt0);
  const int np = nt >> 1;
  const int nc = (p_ >> 1) + 1;                // chunks per pair
  const int slotbase = (bh * CPP + cbase[p_] + ch) * 2;

  const int t = threadIdx.x, w = t >> 6, l = t & 63;
  const int u = w >> 2, w4 = w & 3;
  const int qt = 2 * p_ + u;
  const int q0 = qt * 128 + w4 * 32;
  const int lq = l & 31, hh = l >> 5;
  const int qq = q0 + lq;
  const int nfull = 2 * qt + (w4 >> 1);

  const bf16_t* Qb = Q  + ((size_t)(b * S_ + qq)) * D_ + h * DK_;
  const bf16_t* Kb = K  + ((size_t)b * S_) * D_ + h * DK_;
  const bf16_t* Vb = VT + ((size_t)(b * H_ + h)) * ((size_t)DK_ * S_);

  const int r0 = t >> 3, j0 = t & 7;
  const int jx = (j0 ^ (r0 & 7)) * 8;

  #define STAGE_PAIR(bi, kt_) do {                                        \
    const int kb_ = (kt_) << 6;                                           \
    bf16_t* Lb = lbuf[bi];                                                \
    gl_lds16(Kb + (size_t)(kb_ + r0) * D_ + jx,      Lb + t * 8);         \
    gl_lds16(Kb + (size_t)(kb_ + 64 + r0) * D_ + jx, Lb + 4096 + t * 8);  \
    gl_lds16(Vb + (size_t)r0 * S_ + kb_ + jx,        Lb + 8192 + t * 8);  \
    gl_lds16(Vb + (size_t)r0 * S_ + kb_ + 64 + jx,   Lb + 12288 + t * 8); \
  } while (0)

  bf16x8 qf[4];
  #pragma unroll
  for (int s = 0; s < 4; s++)
    qf[s] = *(const bf16x8*)(Qb + s * 16 + hh * 8);
  asm volatile("s_waitcnt vmcnt(0)" ::: "memory");
  #pragma unroll
  for (int s = 0; s < 4; s++)
    asm volatile("" : "+v"(qf[s]));

  f32x16 o0 = {}, o1 = {};
  f32x16 lacc = {};

  STAGE_PAIR(0, kt0);
  asm volatile("s_waitcnt vmcnt(0)" ::: "memory");
  __builtin_amdgcn_s_barrier();
  __builtin_amdgcn_sched_barrier(0);

  for (int p = 0; p < np; ++p) {
    const int t0 = kt0 + 2 * p, t1 = t0 + 1;
    const int cur = p & 1;

    if (p + 1 < np) STAGE_PAIR(cur ^ 1, t0 + 2);

    const bf16_t* base = lbuf[cur];
    if (t1 <= nfull) {
      f32x16 sa0 = {}, sa1 = {}, sb0 = {}, sb1 = {};
      __builtin_amdgcn_s_setprio(1);
      qkt(base,        qf, lq, hh, sa0, sa1);
      qkt(base + 4096, qf, lq, hh, sb0, sb1);
      __builtin_amdgcn_s_setprio(0);
      if (t1 == nfull) cmask(sb0, sb1, t1 << 6, qq, hh);

      f32x16 pa0, pa1;
      #pragma unroll
      for (int r2 = 0; r2 < 16; r2++) {
        pa0[r2] = fast_exp2(sa0[r2]);
        pa1[r2] = fast_exp2(sa1[r2]);
        lacc[r2] += pa0[r2] + pa1[r2];
      }
      __builtin_amdgcn_s_setprio(1);
      pv_quad(pa0, pa1, base + 8192, lq, hh, o0, o1);
      __builtin_amdgcn_s_setprio(0);

      f32x16 pb0, pb1;
      #pragma unroll
      for (int r2 = 0; r2 < 16; r2++) {
        pb0[r2] = fast_exp2(sb0[r2]);
        pb1[r2] = fast_exp2(sb1[r2]);
        lacc[r2] += pb0[r2] + pb1[r2];
      }
      __builtin_amdgcn_s_setprio(1);
      pv_quad(pb0, pb1, base + 12288, lq, hh, o0, o1);
      __builtin_amdgcn_s_setprio(0);
    } else if (t0 <= nfull) {
      f32x16 sa0 = {}, sa1 = {};
      __builtin_amdgcn_s_setprio(1);
      qkt(base, qf, lq, hh, sa0, sa1);
      __builtin_amdgcn_s_setprio(0);
      cmask(sa0, sa1, t0 << 6, qq, hh);
      f32x16 pa0, pa1;
      #pragma unroll
      for (int r2 = 0; r2 < 16; r2++) {
        pa0[r2] = fast_exp2(sa0[r2]);
        pa1[r2] = fast_exp2(sa1[r2]);
        lacc[r2] += pa0[r2] + pa1[r2];
      }
      __builtin_amdgcn_s_setprio(1);
      pv_quad(pa0, pa1, base + 8192, lq, hh, o0, o1);
      __builtin_amdgcn_s_setprio(0);
    }

    if (p + 1 < np) {
      asm volatile("s_waitcnt vmcnt(0)" ::: "memory");
      __builtin_amdgcn_s_barrier();
      __builtin_amdgcn_sched_barrier(0);
    }
  }
  #undef STAGE_PAIR

  float lrun = 0.f;
  #pragma unroll
  for (int r2 = 0; r2 < 16; r2++) lrun += lacc[r2];
  lrun += __shfl_xor(lrun, 32, 64);

  // ---- write partials
  bf16_t* po = PO + (size_t)(slotbase + u) * 8192;
  #pragma unroll
  for (int r2 = 0; r2 < 16; r2++) {
    int dk = (r2 & 3) + 8 * (r2 >> 2) + 4 * hh;
    po[dk * 128 + w4 * 32 + lq]        = (bf16_t)o0[r2];
    po[(dk + 32) * 128 + w4 * 32 + lq] = (bf16_t)o1[r2];
  }
  if (hh == 0)
    PL[(size_t)(slotbase + u) * 128 + w4 * 32 + lq] = lrun;

  // ---- last-finisher election
  __syncthreads();                       // all partial writes issued
  if (t == 0) {
    __threadfence();                     // release partials (device scope)
    int old = (nc > 1) ? atomicAdd(&CNT[bh * 8 + p_], 1) : 0;
    lastFlag = (nc == 1) || (old == nc - 1);
  }
  __syncthreads();
  if (!lastFlag) return;
  __threadfence();                       // acquire (all threads)

  // ---- combine both q-tiles of this pair (fixed order -> deterministic)
  float* ls  = (float*)&lbuf[0][0];      // [64][132] fp32 = 33.8KB < 64KB
  float* inv = ls + 64 * 132;
  const int t256 = t & 255;

  for (int uu = 0; uu < 2; ++uu) {
    const int slot0 = (bh * CPP + cbase[p_]) * 2 + uu;
    const int qtc = 2 * p_ + uu;

    float acc2[4][8];
    if (t < 256) {
      #pragma unroll
      for (int i = 0; i < 4; i++)
        #pragma unroll
        for (int j = 0; j < 8; j++) acc2[i][j] = 0.f;
      for (int c = 0; c < nc; ++c) {
        const bf16_t* pp = PO + (size_t)(slot0 + 2 * c) * 8192;
        #pragma unroll
        for (int i = 0; i < 4; i++) {
          bf16x8 v = *(const bf16x8*)(pp + i * 2048 + t256 * 8);
          #pragma unroll
          for (int j = 0; j < 8; j++) acc2[i][j] += (float)v[j];
        }
      }
      if (t256 < 128) {
        float s = 0.f;
        for (int c = 0; c < nc; ++c) s += PL[(size_t)(slot0 + 2 * c) * 128 + t256];
        inv[t256] = 1.0f / s;
      }
    }
    __syncthreads();
    if (t < 256) {
      #pragma unroll
      for (int i = 0; i < 4; i++)
        #pragma unroll
        for (int j = 0; j < 8; j++)
          ls[((t256 >> 4) + 16 * i) * 132 + (t256 & 15) * 8 + j] = acc2[i][j];
    }
    __syncthreads();
    if (t < 256) {
      const int q = t256 >> 1, c0 = (t256 & 1) * 32;
      const float iv = inv[q];
      float* op = out + ((size_t)(b * S_ + qtc * 128 + q)) * D_ + h * DK_ + c0;
      #pragma unroll
      for (int v = 0; v < 8; v++) {
        float4 x = { ls[(c0 + 4 * v) * 132 + q] * iv,     ls[(c0 + 4 * v + 1) * 132 + q] * iv,
                     ls[(c0 + 4 * v + 2) * 132 + q] * iv, ls[(c0 + 4 * v + 3) * 132 + q] * iv };
        *(float4*)(op + 4 * v) = x;
      }
    }
    __syncthreads();
  }
}

// ---------------------------------------------------------------------------
extern "C" void kernel_launch(void* const* d_in, const int* in_sizes, int n_in,
                              void* d_out, int out_size, void* d_ws, size_t ws_size,
                              hipStream_t stream) {
  const float* query = (const float*)d_in[0];
  const float* keyi  = (const float*)d_in[1];
  const float* val   = (const float*)d_in[2];
  const float* Wq = (const float*)d_in[4];
  const float* bq = (const float*)d_in[5];
  const float* Wk = (const float*)d_in[6];
  const float* bk = (const float*)d_in[7];
  const float* Wv = (const float*)d_in[8];
  const float* bv = (const float*)d_in[9];
  float* out = (float*)d_out;

  const size_t XB = (size_t)NR * D_;
  const size_t WB = (size_t)D_ * D_;
  bf16_t* ws  = (bf16_t*)d_ws;
  bf16_t* WTq = ws + 3 * XB;
  bf16_t* WTk = WTq + WB;
  bf16_t* WTv = WTk + WB;
  bf16_t* Qm  = WTv + WB;
  bf16_t* Km  = Qm  + XB;
  bf16_t* VTm = Km  + XB;
  bf16_t* PO  = ws;
  float*  PL  = (float*)((char*)d_ws + 22u * 1024 * 1024);
  int*    CNT = (int*)((char*)d_ws + 23u * 1024 * 1024);   // 256 ints

  hipMemsetAsync(CNT, 0, 256 * sizeof(int), stream);

  dim3 tgrid(D_ / 32, D_ / 32, 3), tblk(32, 8);
  transpose_cvt<<<tgrid, tblk, 0, stream>>>(Wq, Wk, Wv, WTq, WTk, WTv);

  dim3 ggrid(NR / 128, D_ / 128, 3);
  gemm_qkv<<<ggrid, 256, 0, stream>>>(query, keyi, val, WTq, WTk, WTv,
                                      bq, bk, bv, Qm, Km, VTm);

  attn_fwd<<<dim3(32 * CPP), 512, 0, stream>>>(Qm, Km, VTm, PO, PL, CNT, out);
}

// Round 21
// 95.374 us; speedup vs baseline: 1.8693x; 1.8693x over previous
//
#include <hip/hip_runtime.h>
#include <hip/hip_bf16.h>

#define B_  2
#define S_  2048
#define D_  1024
#define H_  16
#define DK_ 64
#define NR  (B_*S_)   // 4096 rows
#define QT_ 16        // q-tiles of 128 rows per (b,h)
#define CPP 20        // KV-chunk units per (b,h) (pairs of q-tiles)

typedef __bf16 bf16_t;
typedef __attribute__((ext_vector_type(8)))  __bf16 bf16x8;
typedef __attribute__((ext_vector_type(4)))  float  f32x4;
typedef __attribute__((ext_vector_type(16))) float  f32x16;

// Q pre-scale: 1/sqrt(64) * log2(e)  (attention exp computed in exp2 domain)
#define QSCALE (0.125f * 1.44269504088896340736f)

// ---------------------------------------------------------------------------
__device__ inline void gl_lds16(const void* g, void* l) {
  __builtin_amdgcn_global_load_lds(
      (const __attribute__((address_space(1))) void*)g,
      (__attribute__((address_space(3))) void*)l, 16, 0, 0);
}

__device__ inline unsigned pack2(float a, float b) {
  union { bf16_t h[2]; unsigned u; } x;
  x.h[0] = (bf16_t)a; x.h[1] = (bf16_t)b;
  return x.u;
}

// raw hardware exp2 (r12: −12-15us of VALU vs OCML exp2f without -ffast-math)
__device__ inline float fast_exp2(float x) {
  float r;
  asm("v_exp_f32 %0, %1" : "=v"(r) : "v"(x));
  return r;
}

// swizzled LDS fragment reads; XOR involution matches the staging side.
// 64-col rows (attn): chunk 0..7, XOR row&7 -> 2-way only.
__device__ inline bf16x8 frag(const bf16_t* p, int r, int j) {
  return *(const bf16x8*)(p + r * 64 + ((j ^ (r & 7)) * 8));
}
// 32-col rows (gemm BK=32): XOR (row>>1)&3 -> 2-way only (r15: conflicts 3.1M->0)
__device__ inline bf16x8 frag32(const bf16_t* p, int r, int j) {
  return *(const bf16x8*)(p + r * 32 + ((j ^ ((r >> 1) & 3)) * 8));
}

// pair-chunk decode tables (heaviest-first dispatch order)
__device__ const unsigned char ord_p[CPP] = {7,6,5,4,3,2,7,6,5,4,7,6,1,7,5,3,6,4,2,0};
__device__ const unsigned char ord_c[CPP] = {0,0,0,0,0,0,1,1,1,1,2,2,0,3,2,1,3,2,1,0};
__device__ const unsigned char cbase[8]   = {0,1,2,4,6,9,12,16};

// ---------------------------------------------------------------------------
// W [k][n] fp32 -> WT [n][k] bf16 ; blockIdx.z selects q/k/v
// ---------------------------------------------------------------------------
__global__ void transpose_cvt(const float* __restrict__ wq, const float* __restrict__ wk,
                              const float* __restrict__ wv,
                              bf16_t* __restrict__ oq, bf16_t* __restrict__ ok,
                              bf16_t* __restrict__ ov) {
  const int z = blockIdx.z;
  const float* W = z == 0 ? wq : z == 1 ? wk : wv;
  bf16_t*     WT = z == 0 ? oq : z == 1 ? ok : ov;
  __shared__ float t[32][33];
  int x  = blockIdx.x * 32 + threadIdx.x;
  int y0 = blockIdx.y * 32;
  for (int i = threadIdx.y; i < 32; i += 8)
    t[i][threadIdx.x] = W[(size_t)(y0 + i) * D_ + x];
  __syncthreads();
  int k  = y0 + threadIdx.x;
  int n0 = blockIdx.x * 32;
  for (int i = threadIdx.y; i < 32; i += 8)
    WT[(size_t)(n0 + i) * D_ + k] = (bf16_t)t[threadIdx.x][i];
}

// ---------------------------------------------------------------------------
// C = relu(X @ W + bias) [* scale]; fused fp32-X read (r16 version, best
// measured total). A: reg-staged fp32->bf16 with swizzled LDS write, 1-deep
// lookahead. B: global_load_lds, 2-deep, pre-swizzled source.
// 128x128 tile, BK=32, triple-buffered. z==2 (V): VT, 8B packed stores.
// ---------------------------------------------------------------------------
struct AReg { float4 a[4]; };   // 2 chunks x 8 floats

__global__ __launch_bounds__(256, 3) void gemm_qkv(
    const float* __restrict__ XFq, const float* __restrict__ XFk, const float* __restrict__ XFv,
    const bf16_t* __restrict__ Wq, const bf16_t* __restrict__ Wk, const bf16_t* __restrict__ Wv,
    const float* __restrict__ bq, const float* __restrict__ bk, const float* __restrict__ bv,
    bf16_t* __restrict__ Yq, bf16_t* __restrict__ Yk, bf16_t* __restrict__ Yv)
{
  const int z = blockIdx.z;
  const float*  XF   = z == 0 ? XFq : z == 1 ? XFk : XFv;
  const bf16_t* WT   = z == 0 ? Wq : z == 1 ? Wk : Wv;
  const float*  bias = z == 0 ? bq : z == 1 ? bk : bv;
  bf16_t*       Y    = z == 0 ? Yq : z == 1 ? Yk : Yv;
  const float scale  = z == 0 ? QSCALE : 1.0f;
  const int transposedV = (z == 2);

  __shared__ bf16_t As[3][128 * 32];   // 3 x 8KB (post-cvt bf16)
  __shared__ bf16_t Bs[3][128 * 32];   // 3 x 8KB
  const int m0 = blockIdx.x * 128, n0 = blockIdx.y * 128;
  const int t = threadIdx.x, l = t & 63, w = t >> 6;
  const int wm = (w & 1) * 64, wn = (w >> 1) * 64;
  const int lr = l & 15, lg4 = l >> 4;

  f32x4 acc[4][4] = {};

  // A: load 2 chunks of 8 fp32 from UNswizzled global
  auto loadA = [&](int k0) {
    AReg r;
    #pragma unroll
    for (int i = 0; i < 2; i++) {
      int c = i * 256 + t;
      int row = c >> 2, j = c & 3;
      const float* src = XF + (size_t)(m0 + row) * D_ + k0 + j * 8;
      r.a[2 * i]     = *(const float4*)src;
      r.a[2 * i + 1] = *(const float4*)(src + 4);
    }
    return r;
  };
  // A: cvt to bf16 and write to the SWIZZLED LDS slot (involution w/ frag32)
  auto cvtWriteA = [&](int bi, const AReg& r) {
    #pragma unroll
    for (int i = 0; i < 2; i++) {
      int c = i * 256 + t;
      int row = c >> 2, j = c & 3;
      union { bf16_t h[8]; bf16x8 v; } pk;
      #pragma unroll
      for (int k = 0; k < 4; k++) {
        pk.h[k]     = (bf16_t)r.a[2 * i][k];
        pk.h[4 + k] = (bf16_t)r.a[2 * i + 1][k];
      }
      *(bf16x8*)&As[bi][row * 32 + ((j ^ ((row >> 1) & 3)) * 8)] = pk.v;
    }
  };
  // B: global_load_lds with pre-swizzled source col
  auto stageB = [&](int bi, int k0) {
    #pragma unroll
    for (int i = 0; i < 2; i++) {
      int c = i * 256 + t;
      int row = c >> 2, j = c & 3;
      int sc = (j ^ ((row >> 1) & 3)) * 8;
      gl_lds16(WT + (size_t)(n0 + row) * D_ + k0 + sc, &Bs[bi][c * 8]);
    }
  };

  // ---- prologue: A0,B0,A1,B1; write A0; drain B0; publish buf0
  AReg aA = loadA(0);
  stageB(0, 0);
  AReg aNext = loadA(32);
  stageB(1, 32);
  cvtWriteA(0, aA);
  asm volatile("s_waitcnt vmcnt(6) lgkmcnt(0)" ::: "memory");
  __builtin_amdgcn_s_barrier();
  __builtin_amdgcn_sched_barrier(0);

  const int NSTEP = D_ / 32;   // 32
  for (int p = 0; p < NSTEP; ++p) {
    const int cur = p - (p / 3) * 3;   // p % 3

    AReg aNew;
    const bool more = (p + 2 < NSTEP);
    if (more) {
      const int nb = (p + 2) - ((p + 2) / 3) * 3;
      aNew = loadA((p + 2) * 32);
      stageB(nb, (p + 2) * 32);
    }

    bf16x8 af[4], bfr[4];
    #pragma unroll
    for (int mf = 0; mf < 4; mf++)
      af[mf] = frag32(&As[cur][0], wm + mf * 16 + lr, lg4);
    #pragma unroll
    for (int nf = 0; nf < 4; nf++)
      bfr[nf] = frag32(&Bs[cur][0], wn + nf * 16 + lr, lg4);
    __builtin_amdgcn_s_setprio(1);
    #pragma unroll
    for (int mf = 0; mf < 4; mf++)
      #pragma unroll
      for (int nf = 0; nf < 4; nf++)
        acc[mf][nf] = __builtin_amdgcn_mfma_f32_16x16x32_bf16(
            af[mf], bfr[nf], acc[mf][nf], 0, 0, 0);
    __builtin_amdgcn_s_setprio(0);

    if (p + 1 < NSTEP) {
      const int nb1 = (p + 1) - ((p + 1) / 3) * 3;
      cvtWriteA(nb1, aNext);
      if (more) asm volatile("s_waitcnt vmcnt(6) lgkmcnt(0)" ::: "memory");
      else      asm volatile("s_waitcnt vmcnt(0) lgkmcnt(0)" ::: "memory");
      __builtin_amdgcn_s_barrier();
      __builtin_amdgcn_sched_barrier(0);
      aNext = aNew;
    }
  }

  #pragma unroll
  for (int nf = 0; nf < 4; nf++) {
    int col = n0 + wn + nf * 16 + lr;
    float bvv = bias[col];
    #pragma unroll
    for (int mf = 0; mf < 4; mf++) {
      if (!transposedV) {
        #pragma unroll
        for (int r = 0; r < 4; r++) {
          int row = m0 + wm + mf * 16 + lg4 * 4 + r;
          float v = fmaxf(acc[mf][nf][r] + bvv, 0.f) * scale;
          Y[(size_t)row * D_ + col] = (bf16_t)v;
        }
      } else {
        int row0 = m0 + wm + mf * 16 + lg4 * 4;
        int bb = row0 >> 11, s0 = row0 & (S_ - 1);
        int hh = col >> 6,  dk = col & (DK_ - 1);
        union { bf16_t h[4]; unsigned long long u; } pk;
        #pragma unroll
        for (int r = 0; r < 4; r++)
          pk.h[r] = (bf16_t)fmaxf(acc[mf][nf][r] + bvv, 0.f);
        *(unsigned long long*)&Y[(((size_t)(bb * H_ + hh)) * DK_ + dk) * S_ + s0] = pk.u;
      }
    }
  }
}

// ---------------------------------------------------------------------------
// attention helpers
// ---------------------------------------------------------------------------
__device__ inline void qkt(const bf16_t* kl, const bf16x8* qf, int lq, int hh,
                           f32x16& s0, f32x16& s1) {
  #pragma unroll
  for (int s = 0; s < 4; s++) {
    bf16x8 k0 = frag(kl, lq, 2 * s + hh);
    bf16x8 k1 = frag(kl, lq + 32, 2 * s + hh);
    s0 = __builtin_amdgcn_mfma_f32_32x32x16_bf16(k0, qf[s], s0, 0, 0, 0);
    s1 = __builtin_amdgcn_mfma_f32_32x32x16_bf16(k1, qf[s], s1, 0, 0, 0);
  }
}

__device__ inline void cmask(f32x16& s0, f32x16& s1, int kb, int q, int hh) {
  #pragma unroll
  for (int r = 0; r < 16; r++) {
    int krow = kb + (r & 3) + 8 * (r >> 2) + 4 * hh;
    if (krow > q)      s0[r] = -1e30f;
    if (krow + 32 > q) s1[r] = -1e30f;
  }
}

__device__ inline void pv_quad(const f32x16& p0, const f32x16& p1,
                               const bf16_t* vl, int lq, int hh,
                               f32x16& o0, f32x16& o1) {
  #pragma unroll
  for (int st = 0; st < 4; st++) {
    const f32x16& ps = (st < 2) ? p0 : p1;
    const int bb = (st & 1) * 8;
    unsigned lo0 = pack2(ps[bb + 0], ps[bb + 1]), lo1 = pack2(ps[bb + 2], ps[bb + 3]);
    unsigned hi0 = pack2(ps[bb + 4], ps[bb + 5]), hi1 = pack2(ps[bb + 6], ps[bb + 7]);
    unsigned sA = hh ? lo0 : hi0, sB = hh ? lo1 : hi1;
    unsigned rA = __shfl_xor(sA, 32, 64), rB = __shfl_xor(sB, 32, 64);
    union { unsigned u[4]; bf16x8 v; } pf;
    pf.u[0] = hh ? rA : lo0;  pf.u[1] = hh ? rB : lo1;
    pf.u[2] = hh ? hi0 : rA;  pf.u[3] = hh ? hi1 : rB;
    bf16x8 v0 = frag(vl, lq, 2 * st + hh);
    bf16x8 v1 = frag(vl, lq + 32, 2 * st + hh);
    o0 = __builtin_amdgcn_mfma_f32_32x32x16_bf16(v0, pf.v, o0, 0, 0, 0);
    o1 = __builtin_amdgcn_mfma_f32_32x32x16_bf16(v1, pf.v, o1, 0, 0, 0);
  }
}

// ---------------------------------------------------------------------------
// causal flash attention: 512-thr blocks, K/V staged once per two q-tiles,
// 128 keys (two 64-sub-tiles) per barrier at __launch_bounds__(512,2);
// raw s_barrier + fast_exp2; double-buffer 2x32KB = 64KB -> 2 blocks/CU.
// ---------------------------------------------------------------------------
__global__ __launch_bounds__(512, 2) void attn_fwd(
    const bf16_t* __restrict__ Q, const bf16_t* __restrict__ K,
    const bf16_t* __restrict__ VT, bf16_t* __restrict__ PO,
    float* __restrict__ PL)
{
  __shared__ bf16_t lbuf[2][16384];  // per buf: K0|K1|V0|V1 x 4096 elems

  const int bx = blockIdx.x;
  const int unit = bx >> 5, bh = bx & 31;
  const int p_ = ord_p[unit], ch = ord_c[unit];
  const int b = bh >> 4, h = bh & 15;
  const int kt0 = ch * 8;
  const int nt = min(8, (4 * p_ + 4) - kt0);   // in {4,8}
  const int np = nt >> 1;                      // pair-iterations {2,4}
  const int slotbase = (bh * CPP + cbase[p_] + ch) * 2;

  const int t = threadIdx.x, w = t >> 6, l = t & 63;
  const int u = w >> 2, w4 = w & 3;
  const int qt = 2 * p_ + u;
  const int q0 = qt * 128 + w4 * 32;
  const int lq = l & 31, hh = l >> 5;
  const int qq = q0 + lq;
  const int nfull = 2 * qt + (w4 >> 1);        // this wave's diagonal 64-tile

  const bf16_t* Qb = Q  + ((size_t)(b * S_ + qq)) * D_ + h * DK_;
  const bf16_t* Kb = K  + ((size_t)b * S_) * D_ + h * DK_;
  const bf16_t* Vb = VT + ((size_t)(b * H_ + h)) * ((size_t)DK_ * S_);

  // staging coords: thread t -> (row r0 in 0..63, swizzled 16B chunk jx)
  const int r0 = t >> 3, j0 = t & 7;
  const int jx = (j0 ^ (r0 & 7)) * 8;

  // stage one PAIR of 64-tiles (K 16KB + V 16KB): 4 gl_lds16 per thread
  #define STAGE_PAIR(bi, kt_) do {                                        \
    const int kb_ = (kt_) << 6;                                           \
    bf16_t* Lb = lbuf[bi];                                                \
    gl_lds16(Kb + (size_t)(kb_ + r0) * D_ + jx,      Lb + t * 8);         \
    gl_lds16(Kb + (size_t)(kb_ + 64 + r0) * D_ + jx, Lb + 4096 + t * 8);  \
    gl_lds16(Vb + (size_t)r0 * S_ + kb_ + jx,        Lb + 8192 + t * 8);  \
    gl_lds16(Vb + (size_t)r0 * S_ + kb_ + 64 + jx,   Lb + 12288 + t * 8); \
  } while (0)

  bf16x8 qf[4];
  #pragma unroll
  for (int s = 0; s < 4; s++)
    qf[s] = *(const bf16x8*)(Qb + s * 16 + hh * 8);
  asm volatile("s_waitcnt vmcnt(0)" ::: "memory");
  #pragma unroll
  for (int s = 0; s < 4; s++)
    asm volatile("" : "+v"(qf[s]));

  f32x16 o0 = {}, o1 = {};            // O^T: col=q (lane), rows=dk
  f32x16 lacc = {};                   // deferred l accumulator

  // ---- prologue: stage pair 0
  STAGE_PAIR(0, kt0);
  asm volatile("s_waitcnt vmcnt(0)" ::: "memory");
  __builtin_amdgcn_s_barrier();
  __builtin_amdgcn_sched_barrier(0);

  for (int p = 0; p < np; ++p) {
    const int t0 = kt0 + 2 * p, t1 = t0 + 1;
    const int cur = p & 1;

    if (p + 1 < np) STAGE_PAIR(cur ^ 1, t0 + 2);

    const bf16_t* base = lbuf[cur];
    if (t1 <= nfull) {
      // ---- both sub-tiles active (common case)
      f32x16 sa0 = {}, sa1 = {}, sb0 = {}, sb1 = {};
      __builtin_amdgcn_s_setprio(1);
      qkt(base,        qf, lq, hh, sa0, sa1);
      qkt(base + 4096, qf, lq, hh, sb0, sb1);
      __builtin_amdgcn_s_setprio(0);
      if (t1 == nfull) cmask(sb0, sb1, t1 << 6, qq, hh);

      f32x16 pa0, pa1;
      #pragma unroll
      for (int r2 = 0; r2 < 16; r2++) {
        pa0[r2] = fast_exp2(sa0[r2]);
        pa1[r2] = fast_exp2(sa1[r2]);
        lacc[r2] += pa0[r2] + pa1[r2];
      }
      __builtin_amdgcn_s_setprio(1);
      pv_quad(pa0, pa1, base + 8192, lq, hh, o0, o1);
      __builtin_amdgcn_s_setprio(0);

      f32x16 pb0, pb1;
      #pragma unroll
      for (int r2 = 0; r2 < 16; r2++) {
        pb0[r2] = fast_exp2(sb0[r2]);
        pb1[r2] = fast_exp2(sb1[r2]);
        lacc[r2] += pb0[r2] + pb1[r2];
      }
      __builtin_amdgcn_s_setprio(1);
      pv_quad(pb0, pb1, base + 12288, lq, hh, o0, o1);
      __builtin_amdgcn_s_setprio(0);
    } else if (t0 <= nfull) {
      // ---- only sub-tile a (wave diagonal ends here; t0 == nfull)
      f32x16 sa0 = {}, sa1 = {};
      __builtin_amdgcn_s_setprio(1);
      qkt(base, qf, lq, hh, sa0, sa1);
      __builtin_amdgcn_s_setprio(0);
      cmask(sa0, sa1, t0 << 6, qq, hh);
      f32x16 pa0, pa1;
      #pragma unroll
      for (int r2 = 0; r2 < 16; r2++) {
        pa0[r2] = fast_exp2(sa0[r2]);
        pa1[r2] = fast_exp2(sa1[r2]);
        lacc[r2] += pa0[r2] + pa1[r2];
      }
      __builtin_amdgcn_s_setprio(1);
      pv_quad(pa0, pa1, base + 8192, lq, hh, o0, o1);
      __builtin_amdgcn_s_setprio(0);
    }

    if (p + 1 < np) {
      asm volatile("s_waitcnt vmcnt(0)" ::: "memory");
      __builtin_amdgcn_s_barrier();
      __builtin_amdgcn_sched_barrier(0);
    }
  }
  #undef STAGE_PAIR

  // ---- final l reduce (deferred)
  float lrun = 0.f;
  #pragma unroll
  for (int r2 = 0; r2 < 16; r2++) lrun += lacc[r2];
  lrun += __shfl_xor(lrun, 32, 64);

  // ---- epilogue: write UNNORMALIZED partial O^T (bf16) + l (fp32)
  bf16_t* po = PO + (size_t)(slotbase + u) * 8192;
  #pragma unroll
  for (int r2 = 0; r2 < 16; r2++) {
    int dk = (r2 & 3) + 8 * (r2 >> 2) + 4 * hh;
    po[dk * 128 + w4 * 32 + lq]        = (bf16_t)o0[r2];
    po[(dk + 32) * 128 + w4 * 32 + lq] = (bf16_t)o1[r2];
  }
  if (hh == 0)
    PL[(size_t)(slotbase + u) * 128 + w4 * 32 + lq] = lrun;
}

// ---------------------------------------------------------------------------
__global__ __launch_bounds__(256, 4) void attn_combine(
    const bf16_t* __restrict__ PO, const float* __restrict__ PL,
    float* __restrict__ out)
{
  const int bx = blockIdx.x;
  const int b = bx >> 8, h = (bx >> 4) & 15, qt = bx & 15;
  const int bh = b * H_ + h;
  const int p_ = qt >> 1, u = qt & 1;
  const int nc = (p_ >> 1) + 1;
  const int slot0 = (bh * CPP + cbase[p_]) * 2 + u;

  __shared__ float ls[64][132];
  __shared__ float inv[128];

  const int t = threadIdx.x;

  float acc[4][8];
  #pragma unroll
  for (int i = 0; i < 4; i++)
    #pragma unroll
    for (int j = 0; j < 8; j++) acc[i][j] = 0.f;

  for (int c = 0; c < nc; ++c) {
    const bf16_t* po = PO + (size_t)(slot0 + 2 * c) * 8192;
    #pragma unroll
    for (int i = 0; i < 4; i++) {
      bf16x8 v = *(const bf16x8*)(po + i * 2048 + t * 8);
      #pragma unroll
      for (int j = 0; j < 8; j++) acc[i][j] += (float)v[j];
    }
  }

  if (t < 128) {
    float s = 0.f;
    for (int c = 0; c < nc; ++c) s += PL[(size_t)(slot0 + 2 * c) * 128 + t];
    inv[t] = 1.0f / s;
  }

  #pragma unroll
  for (int i = 0; i < 4; i++)
    #pragma unroll
    for (int j = 0; j < 8; j++)
      ls[(t >> 4) + 16 * i][(t & 15) * 8 + j] = acc[i][j];
  __syncthreads();

  const int q = t >> 1, c0 = (t & 1) * 32;
  const float iv = inv[q];
  float* op = out + ((size_t)(b * S_ + qt * 128 + q)) * D_ + h * DK_ + c0;
  #pragma unroll
  for (int v = 0; v < 8; v++) {
    float4 x = { ls[c0 + 4 * v][q] * iv,     ls[c0 + 4 * v + 1][q] * iv,
                 ls[c0 + 4 * v + 2][q] * iv, ls[c0 + 4 * v + 3][q] * iv };
    *(float4*)(op + 4 * v) = x;
  }
}

// ---------------------------------------------------------------------------
extern "C" void kernel_launch(void* const* d_in, const int* in_sizes, int n_in,
                              void* d_out, int out_size, void* d_ws, size_t ws_size,
                              hipStream_t stream) {
  const float* query = (const float*)d_in[0];
  const float* keyi  = (const float*)d_in[1];
  const float* val   = (const float*)d_in[2];
  const float* Wq = (const float*)d_in[4];
  const float* bq = (const float*)d_in[5];
  const float* Wk = (const float*)d_in[6];
  const float* bk = (const float*)d_in[7];
  const float* Wv = (const float*)d_in[8];
  const float* bv = (const float*)d_in[9];
  float* out = (float*)d_out;

  const size_t XB = (size_t)NR * D_;
  const size_t WB = (size_t)D_ * D_;
  bf16_t* ws  = (bf16_t*)d_ws;
  bf16_t* WTq = ws + 3 * XB;
  bf16_t* WTk = WTq + WB;
  bf16_t* WTv = WTk + WB;
  bf16_t* Qm  = WTv + WB;
  bf16_t* Km  = Qm  + XB;
  bf16_t* VTm = Km  + XB;
  bf16_t* PO  = ws;
  float*  PL  = (float*)((char*)d_ws + 22u * 1024 * 1024);

  dim3 tgrid(D_ / 32, D_ / 32, 3), tblk(32, 8);
  transpose_cvt<<<tgrid, tblk, 0, stream>>>(Wq, Wk, Wv, WTq, WTk, WTv);

  dim3 ggrid(NR / 128, D_ / 128, 3);
  gemm_qkv<<<ggrid, 256, 0, stream>>>(query, keyi, val, WTq, WTk, WTv,
                                      bq, bk, bv, Qm, Km, VTm);

  attn_fwd<<<dim3(32 * CPP), 512, 0, stream>>>(Qm, Km, VTm, PO, PL);
  attn_combine<<<dim3(B_ * H_ * QT_), 256, 0, stream>>>(PO, PL, out);
}